// Round 1
// baseline (1538.263 us; speedup 1.0000x reference)
//
#include <hip/hip_runtime.h>
#include <stdint.h>

typedef __attribute__((ext_vector_type(8))) short short8;
typedef __attribute__((ext_vector_type(4))) float f32x4;

__device__ __forceinline__ unsigned short f2bf(float f) {
  union { float f; uint32_t u; } v; v.f = f;
  uint32_t u = v.u;
  u += 0x7FFF + ((u >> 16) & 1);   // round-to-nearest-even
  return (unsigned short)(u >> 16);
}
__device__ __forceinline__ float bf2f(unsigned short h) {
  union { uint32_t u; float f; } v; v.u = ((uint32_t)h) << 16;
  return v.f;
}

// ---------------- convert fp32 -> bf16 (vectorized, 8 elems/thread) -------
__global__ void conv_kernel(const float* __restrict__ in,
                            unsigned short* __restrict__ out, int n) {
  long i = ((long)blockIdx.x * blockDim.x + threadIdx.x) * 8;
  if (i >= n) return;
  float4 a = *(const float4*)(in + i);
  float4 b = *(const float4*)(in + i + 4);
  short8 s;
  s[0] = (short)f2bf(a.x); s[1] = (short)f2bf(a.y);
  s[2] = (short)f2bf(a.z); s[3] = (short)f2bf(a.w);
  s[4] = (short)f2bf(b.x); s[5] = (short)f2bf(b.y);
  s[6] = (short)f2bf(b.z); s[7] = (short)f2bf(b.w);
  *(short8*)(out + i) = s;
}

// ---------------- bf16 GEMM, C = A @ W^T (+ epilogue) ---------------------
// A: [M,K] bf16 row-major (row stride lda); W: [N,K] bf16 (row stride ldw)
// 128x128 tile, BK=32, 4 waves, each wave a 64x64 quadrant (4x4 frags of
// 16x16x32 MFMA). global_load_lds width=16 staging, linear LDS [128][32].
enum { EPI_BIAS = 0, EPI_ADD = 1, EPI_GATE = 2, EPI_F32 = 3 };

template <int EPI>
__global__ void gemm_bt_kernel(const unsigned short* __restrict__ A, int lda,
                               const unsigned short* __restrict__ W, int ldw,
                               const float* __restrict__ bias,
                               const unsigned short* __restrict__ X1,
                               const unsigned short* __restrict__ X2,
                               const unsigned short* __restrict__ X3,
                               void* __restrict__ Cv, int N, int K) {
  constexpr int BK = 32;
  __shared__ unsigned short sA[128 * BK];
  __shared__ unsigned short sB[128 * BK];
  const int tid  = threadIdx.x;
  const int lane = tid & 63;
  const int wave = tid >> 6;
  const int wr = (wave >> 1) * 64;   // wave row offset in tile
  const int wc = (wave & 1) * 64;    // wave col offset in tile
  const long tileM = (long)blockIdx.y * 128;
  const long tileN = (long)blockIdx.x * 128;

  // staging: thread t loads 16B = 8 bf16 at tile row t/4, k-chunk t%4 (and +64 rows)
  const unsigned short* gA = A + (tileM + (tid >> 2)) * (long)lda + (tid & 3) * 8;
  const unsigned short* gB = W + (tileN + (tid >> 2)) * (long)ldw + (tid & 3) * 8;
  unsigned short* lA = sA + wave * 512;  // wave-uniform LDS base (lane x 16B applied by HW)
  unsigned short* lB = sB + wave * 512;

  f32x4 acc[4][4] = {};
  const int fr = lane & 15;          // fragment row (A) / col (B)
  const int kb = (lane >> 4) * 8;    // fragment k base

  for (int k0 = 0; k0 < K; k0 += BK) {
    __builtin_amdgcn_global_load_lds(
        (const __attribute__((address_space(1))) void*)(gA + k0),
        (__attribute__((address_space(3))) void*)(lA), 16, 0, 0);
    __builtin_amdgcn_global_load_lds(
        (const __attribute__((address_space(1))) void*)(gA + k0 + 64 * (long)lda),
        (__attribute__((address_space(3))) void*)(lA + 2048), 16, 0, 0);
    __builtin_amdgcn_global_load_lds(
        (const __attribute__((address_space(1))) void*)(gB + k0),
        (__attribute__((address_space(3))) void*)(lB), 16, 0, 0);
    __builtin_amdgcn_global_load_lds(
        (const __attribute__((address_space(1))) void*)(gB + k0 + 64 * (long)ldw),
        (__attribute__((address_space(3))) void*)(lB + 2048), 16, 0, 0);
    __syncthreads();  // drains vmcnt, LDS tiles ready

    short8 aF[4], bF[4];
#pragma unroll
    for (int m = 0; m < 4; ++m)
      aF[m] = *(const short8*)&sA[(wr + m * 16 + fr) * BK + kb];
#pragma unroll
    for (int n = 0; n < 4; ++n)
      bF[n] = *(const short8*)&sB[(wc + n * 16 + fr) * BK + kb];
#pragma unroll
    for (int m = 0; m < 4; ++m)
#pragma unroll
      for (int n = 0; n < 4; ++n)
        acc[m][n] = __builtin_amdgcn_mfma_f32_16x16x32_bf16(aF[m], bF[n], acc[m][n], 0, 0, 0);
    __syncthreads();  // protect LDS before next staging
  }

  // epilogue: C/D layout col = lane&15, row = (lane>>4)*4 + reg
  const int cr = (lane >> 4) * 4;
  const int cc = lane & 15;
#pragma unroll
  for (int m = 0; m < 4; ++m) {
    long r0 = tileM + wr + m * 16 + cr;
#pragma unroll
    for (int n = 0; n < 4; ++n) {
      long c = tileN + wc + n * 16 + cc;
      float bv = bias ? bias[c] : 0.0f;
#pragma unroll
      for (int r = 0; r < 4; ++r) {
        long idx = (r0 + r) * (long)N + c;
        float v = acc[m][n][r] + bv;
        if constexpr (EPI == EPI_ADD) {
          v += bf2f(X1[idx]);
        }
        if constexpr (EPI == EPI_GATE) {
          // acc = cross@gw_c^T ; X1 = glog = g@gw_g^T ; bias = gate_b
          float logit = v + bf2f(X1[idx]);
          float gt = 1.0f / (1.0f + expf(-logit));
          float gv = bf2f(X2[idx]);   // g
          float cv = bf2f(X3[idx]);   // cross
          v = gt * gv + (1.0f - gt) * cv + gv;  // fused + residual g (pre-LN)
        }
        if constexpr (EPI == EPI_F32)
          ((float*)Cv)[idx] = v;
        else
          ((unsigned short*)Cv)[idx] = f2bf(v);
      }
    }
  }
}

// ---------------- row LayerNorm over 2048 cols ----------------------------
__global__ __launch_bounds__(256) void ln_kernel(
    const unsigned short* __restrict__ in, const float* __restrict__ gamma,
    const float* __restrict__ beta, unsigned short* __restrict__ out) {
  const int row = blockIdx.x;
  const int t = threadIdx.x;          // 256 threads x 8 elems = 2048
  const int lane = t & 63, wave = t >> 6;
  const unsigned short* rp = in + (long)row * 2048;
  short8 v8 = *(const short8*)&rp[t * 8];
  float v[8];
  float s = 0.f, s2 = 0.f;
#pragma unroll
  for (int j = 0; j < 8; ++j) {
    v[j] = bf2f((unsigned short)v8[j]);
    s += v[j];
    s2 += v[j] * v[j];
  }
#pragma unroll
  for (int off = 1; off < 64; off <<= 1) {
    s  += __shfl_xor(s, off);
    s2 += __shfl_xor(s2, off);
  }
  __shared__ float red[8];
  if (lane == 0) { red[wave] = s; red[4 + wave] = s2; }
  __syncthreads();
  float ts  = red[0] + red[1] + red[2] + red[3];
  float ts2 = red[4] + red[5] + red[6] + red[7];
  float mean = ts * (1.0f / 2048.0f);
  float var  = ts2 * (1.0f / 2048.0f) - mean * mean;
  float inv  = rsqrtf(var + 1e-5f);
  short8 o8;
#pragma unroll
  for (int j = 0; j < 8; ++j) {
    float o = (v[j] - mean) * inv * gamma[t * 8 + j] + beta[t * 8 + j];
    o8[j] = (short)f2bf(o);
  }
  *(short8*)(out + (long)row * 2048 + t * 8) = o8;
}

// --------------------------------------------------------------------------
extern "C" void kernel_launch(void* const* d_in, const int* in_sizes, int n_in,
                              void* d_out, int out_size, void* d_ws, size_t ws_size,
                              hipStream_t stream) {
  const float* graph    = (const float*)d_in[0];
  const float* temporal = (const float*)d_in[1];
  const float* gp_w  = (const float*)d_in[2];
  const float* gp_b  = (const float*)d_in[3];
  const float* tp_w  = (const float*)d_in[4];
  const float* tp_b  = (const float*)d_in[5];
  const float* in1_w = (const float*)d_in[6];
  const float* in1_b = (const float*)d_in[7];
  const float* out1_w = (const float*)d_in[8];
  const float* out1_b = (const float*)d_in[9];
  const float* in2_w = (const float*)d_in[10];
  const float* in2_b = (const float*)d_in[11];
  const float* out2_w = (const float*)d_in[12];
  const float* out2_b = (const float*)d_in[13];
  const float* gate_w = (const float*)d_in[14];
  const float* gate_b = (const float*)d_in[15];
  const float* ln_g  = (const float*)d_in[16];
  const float* ln_b  = (const float*)d_in[17];
  const float* lin_w = (const float*)d_in[18];
  const float* lin_b = (const float*)d_in[19];

  const int Bm = 16384, F = 2048, GD = 1024;
  const long BF = (long)Bm * F;      // 33,554,432
  const long BG = (long)Bm * GD;     // 16,777,216

  // ws layout (256 MB): S0 (g), S1 (t/v2/glog/ln), inG, inT, weights (64MB)
  unsigned short* S0  = (unsigned short*)d_ws;
  unsigned short* S1  = S0 + BF;
  unsigned short* inG = S1 + BF;
  unsigned short* inT = inG + BG;
  unsigned short* wGP   = inT + BG;
  unsigned short* wTP   = wGP + (long)F * GD;
  unsigned short* wV1   = wTP + (long)F * GD;
  unsigned short* wO1   = wV1 + (long)F * F;
  unsigned short* wV2   = wO1 + (long)F * F;
  unsigned short* wO2   = wV2 + (long)F * F;
  unsigned short* wGATE = wO2 + (long)F * F;
  unsigned short* wLIN  = wGATE + (long)F * 2 * F;
  // d_out (134MB fp32) doubles as bf16 scratch until final GEMM:
  unsigned short* S2 = (unsigned short*)d_out;  // v1, then cross
  unsigned short* S3 = S2 + BF;                 // a1, then pre-LN

  auto conv = [&](const float* src, unsigned short* dst, long n) {
    conv_kernel<<<dim3((unsigned)((n / 8 + 255) / 256)), 256, 0, stream>>>(src, dst, (int)n);
  };
  conv(graph, inG, BG);
  conv(temporal, inT, BG);
  conv(gp_w, wGP, (long)F * GD);
  conv(tp_w, wTP, (long)F * GD);
  conv(in1_w + (long)2 * F * F, wV1, (long)F * F);   // only v-slice matters (softmax==1)
  conv(out1_w, wO1, (long)F * F);
  conv(in2_w + (long)2 * F * F, wV2, (long)F * F);
  conv(out2_w, wO2, (long)F * F);
  conv(gate_w, wGATE, (long)F * 2 * F);
  conv(lin_w, wLIN, (long)F * F);

  dim3 blk(256);
  dim3 gF(F / 128, Bm / 128);  // (16, 128)

  // K1: g = graph @ gp_w^T + gp_b
  gemm_bt_kernel<EPI_BIAS><<<gF, blk, 0, stream>>>(inG, GD, wGP, GD, gp_b,
      nullptr, nullptr, nullptr, S0, F, GD);
  // K2: t = temporal @ tp_w^T + tp_b
  gemm_bt_kernel<EPI_BIAS><<<gF, blk, 0, stream>>>(inT, GD, wTP, GD, tp_b,
      nullptr, nullptr, nullptr, S1, F, GD);
  // K3: v1 = t @ wv1^T + bv1
  gemm_bt_kernel<EPI_BIAS><<<gF, blk, 0, stream>>>(S1, F, wV1, F, in1_b + 2 * F,
      nullptr, nullptr, nullptr, S2, F, F);
  // K4: v2 = g @ wv2^T + bv2
  gemm_bt_kernel<EPI_BIAS><<<gF, blk, 0, stream>>>(S0, F, wV2, F, in2_b + 2 * F,
      nullptr, nullptr, nullptr, S1, F, F);
  // K5: a1 = v1 @ out1_w^T + out1_b
  gemm_bt_kernel<EPI_BIAS><<<gF, blk, 0, stream>>>(S2, F, wO1, F, out1_b,
      nullptr, nullptr, nullptr, S3, F, F);
  // K6: cross = v2 @ out2_w^T + out2_b + a1
  gemm_bt_kernel<EPI_ADD><<<gF, blk, 0, stream>>>(S1, F, wO2, F, out2_b,
      S3, nullptr, nullptr, S2, F, F);
  // K7: glog = g @ gw_g^T   (gate_w cols 0:F, row stride 2F)
  gemm_bt_kernel<EPI_BIAS><<<gF, blk, 0, stream>>>(S0, F, wGATE, 2 * F, nullptr,
      nullptr, nullptr, nullptr, S1, F, F);
  // K8: pre-LN = gate*g + (1-gate)*cross + g ; gate = sigmoid(cross@gw_c^T + glog + gate_b)
  gemm_bt_kernel<EPI_GATE><<<gF, blk, 0, stream>>>(S2, F, wGATE + F, 2 * F, gate_b,
      S1, S0, S2, S3, F, F);
  // K9: LayerNorm
  ln_kernel<<<dim3(Bm), blk, 0, stream>>>(S3, ln_g, ln_b, S1);
  // K10: out = ln @ lin_w^T + lin_b  (fp32 out)
  gemm_bt_kernel<EPI_F32><<<gF, blk, 0, stream>>>(S1, F, wLIN, F, lin_b,
      nullptr, nullptr, nullptr, (void*)d_out, F, F);
}

// Round 2
// 1353.858 us; speedup vs baseline: 1.1362x; 1.1362x over previous
//
#include <hip/hip_runtime.h>
#include <stdint.h>

typedef __attribute__((ext_vector_type(8))) short short8;
typedef __attribute__((ext_vector_type(4))) float f32x4;

__device__ __forceinline__ unsigned short f2bf(float f) {
  union { float f; uint32_t u; } v; v.f = f;
  uint32_t u = v.u;
  u += 0x7FFF + ((u >> 16) & 1);   // round-to-nearest-even
  return (unsigned short)(u >> 16);
}
__device__ __forceinline__ float bf2f(unsigned short h) {
  union { uint32_t u; float f; } v; v.u = ((uint32_t)h) << 16;
  return v.f;
}

// ---------------- convert fp32 -> bf16 (vectorized, 8 elems/thread) -------
__global__ void conv_kernel(const float* __restrict__ in,
                            unsigned short* __restrict__ out, int n) {
  long i = ((long)blockIdx.x * blockDim.x + threadIdx.x) * 8;
  if (i >= n) return;
  float4 a = *(const float4*)(in + i);
  float4 b = *(const float4*)(in + i + 4);
  short8 s;
  s[0] = (short)f2bf(a.x); s[1] = (short)f2bf(a.y);
  s[2] = (short)f2bf(a.z); s[3] = (short)f2bf(a.w);
  s[4] = (short)f2bf(b.x); s[5] = (short)f2bf(b.y);
  s[6] = (short)f2bf(b.z); s[7] = (short)f2bf(b.w);
  *(short8*)(out + i) = s;
}

// ---------------- 256x256 bf16 GEMM, C = A @ W^T (+ epilogue) -------------
// BK=32, 8 waves (2M x 4N), wave tile 128x64, ring-4 LDS double... quad-buffer,
// counted vmcnt(12) (3-tile prefetch lead), T2 chunk-XOR swizzle both-sides,
// XCD-chunked block swizzle, setprio around MFMA cluster.
// K-split support: for k0 >= KSPLIT read A2/W2 (same lda/ldw). For contiguous
// buffers pass P2 = P1 + KSPLIT.
enum { EPI_BIAS = 0, EPI_GATE = 2, EPI_F32 = 3 };

template <int EPI>
__global__ __launch_bounds__(512, 2)
void gemm256_kernel(const unsigned short* __restrict__ A1,
                    const unsigned short* __restrict__ A2, int lda,
                    const unsigned short* __restrict__ W1,
                    const unsigned short* __restrict__ W2, int ldw,
                    int K, int KSPLIT,
                    const float* __restrict__ bias,
                    const float* __restrict__ bias2,
                    const unsigned short* __restrict__ Xg,
                    const unsigned short* __restrict__ Xc,
                    void* __restrict__ Cv) {
  constexpr int BK = 32;
  constexpr int N = 2048;
  __shared__ unsigned short smem[4 * 16384];  // 128 KB: 4 bufs x (A 16KB + B 16KB)

  const int tid  = threadIdx.x;
  const int lane = tid & 63;
  const int w    = tid >> 6;       // wave 0..7
  const int wm   = w >> 2;         // 0..1  (M half of tile)
  const int wn   = w & 3;          // 0..3  (N quarter)

  // XCD-chunked swizzle: 512 blocks = 8 n-tiles x 64 m-tiles, M-fast per XCD
  const int swz = (blockIdx.x & 7) * 64 + (blockIdx.x >> 3);
  const int mt = swz & 63;
  const int nt = swz >> 6;
  const long tileM = (long)mt * 256;
  const long tileN = (long)nt * 256;

  // ---- staging descriptors (per lane). One global_load_lds = 64 lanes x 16B
  // = 16 rows x 64B (row = 32 bf16). Wave w instr j covers rows w*32+j*16..+15.
  // LDS dest is linear; source chunk is inverse-swizzled: lc = pc ^ ((row>>1)&3)
  // where pc = lane&3 and (row>>1)&3 == (lane>>3)&3 for this row mapping.
  const int srow = w * 32 + (lane >> 2);
  const int lc   = (lane & 3) ^ ((lane >> 3) & 3);
  const unsigned short* pA1 = A1 + (tileM + srow) * (long)lda + lc * 8;
  const unsigned short* pA2 = A2 + (tileM + srow) * (long)lda + lc * 8;
  const unsigned short* pB1 = W1 + (tileN + srow) * (long)ldw + lc * 8;
  const unsigned short* pB2 = W2 + (tileN + srow) * (long)ldw + lc * 8;
  unsigned short* lA = smem + w * 32 * 32;          // + buf*16384
  unsigned short* lB = smem + 8192 + w * 32 * 32;

  const int NT = K / BK;

#define STAGE(kt_)                                                            \
  {                                                                           \
    const int kt__ = (kt_);                                                   \
    const int k0__ = kt__ * BK;                                               \
    const unsigned short* a_ =                                                \
        (k0__ < KSPLIT) ? (pA1 + k0__) : (pA2 + (k0__ - KSPLIT));             \
    const unsigned short* b_ =                                                \
        (k0__ < KSPLIT) ? (pB1 + k0__) : (pB2 + (k0__ - KSPLIT));             \
    unsigned short* la_ = lA + (kt__ & 3) * 16384;                            \
    unsigned short* lb_ = lB + (kt__ & 3) * 16384;                            \
    __builtin_amdgcn_global_load_lds(                                         \
        (const __attribute__((address_space(1))) void*)a_,                    \
        (__attribute__((address_space(3))) void*)la_, 16, 0, 0);              \
    __builtin_amdgcn_global_load_lds(                                         \
        (const __attribute__((address_space(1))) void*)(a_ + 16 * (long)lda), \
        (__attribute__((address_space(3))) void*)(la_ + 16 * 32), 16, 0, 0);  \
    __builtin_amdgcn_global_load_lds(                                         \
        (const __attribute__((address_space(1))) void*)b_,                    \
        (__attribute__((address_space(3))) void*)(lb_), 16, 0, 0);            \
    __builtin_amdgcn_global_load_lds(                                         \
        (const __attribute__((address_space(1))) void*)(b_ + 16 * (long)ldw), \
        (__attribute__((address_space(3))) void*)(lb_ + 16 * 32), 16, 0, 0);  \
  }

  f32x4 acc[8][4] = {};
  const int fr = lane & 15;                        // frag row/col
  const int pc = (lane >> 4) ^ ((fr >> 1) & 3);    // swizzled physical chunk
  const unsigned short* rA = smem + (wm * 128 + fr) * 32 + pc * 8;
  const unsigned short* rB = smem + 8192 + (wn * 64 + fr) * 32 + pc * 8;

  STAGE(0); STAGE(1); STAGE(2);

  for (int kt = 0; kt < NT; ++kt) {
    if (kt + 3 < NT) STAGE(kt + 3);
    __builtin_amdgcn_sched_barrier(0);
    const int rem = NT - 1 - kt;
    if (rem >= 3)      asm volatile("s_waitcnt vmcnt(12)" ::: "memory");
    else if (rem == 2) asm volatile("s_waitcnt vmcnt(8)"  ::: "memory");
    else if (rem == 1) asm volatile("s_waitcnt vmcnt(4)"  ::: "memory");
    else               asm volatile("s_waitcnt vmcnt(0)"  ::: "memory");
    __builtin_amdgcn_s_barrier();          // tile kt fully in LDS for all waves
    __builtin_amdgcn_sched_barrier(0);

    const unsigned short* ra = rA + (kt & 3) * 16384;
    const unsigned short* rb = rB + (kt & 3) * 16384;
    short8 aF[8], bF[4];
#pragma unroll
    for (int m = 0; m < 8; ++m) aF[m] = *(const short8*)(ra + m * 16 * 32);
#pragma unroll
    for (int n = 0; n < 4; ++n) bF[n] = *(const short8*)(rb + n * 16 * 32);
    __builtin_amdgcn_s_setprio(1);
#pragma unroll
    for (int m = 0; m < 8; ++m)
#pragma unroll
      for (int n = 0; n < 4; ++n)
        acc[m][n] = __builtin_amdgcn_mfma_f32_16x16x32_bf16(aF[m], bF[n], acc[m][n], 0, 0, 0);
    __builtin_amdgcn_s_setprio(0);
    __builtin_amdgcn_sched_barrier(0);
    asm volatile("s_waitcnt lgkmcnt(0)" ::: "memory");  // own reads complete
    __builtin_amdgcn_s_barrier();          // all reads of buf[kt&3] done before reuse
  }
#undef STAGE

  // epilogue: C/D layout col = lane&15, row = (lane>>4)*4 + reg
  const int cr = (lane >> 4) * 4;
  const int cc = lane & 15;
#pragma unroll
  for (int m = 0; m < 8; ++m) {
    long rr = tileM + wm * 128 + m * 16 + cr;
#pragma unroll
    for (int n = 0; n < 4; ++n) {
      long c = tileN + wn * 64 + n * 16 + cc;
      float bv = (bias ? bias[c] : 0.0f) + (bias2 ? bias2[c] : 0.0f);
#pragma unroll
      for (int r = 0; r < 4; ++r) {
        long idx = (rr + r) * (long)N + c;
        float v = acc[m][n][r] + bv;
        if constexpr (EPI == EPI_GATE) {
          // v = logit = concat(g,cross)@gate_w^T + gate_b  (K=4096 covered both)
          float gt = 1.0f / (1.0f + expf(-v));
          float gv = bf2f(Xg[idx]);   // g
          float cv = bf2f(Xc[idx]);   // cross
          v = gt * gv + (1.0f - gt) * cv + gv;  // fused + residual g (pre-LN)
        }
        if constexpr (EPI == EPI_F32)
          ((float*)Cv)[idx] = v;
        else
          ((unsigned short*)Cv)[idx] = f2bf(v);
      }
    }
  }
}

// ---------------- row LayerNorm over 2048 cols ----------------------------
__global__ __launch_bounds__(256) void ln_kernel(
    const unsigned short* __restrict__ in, const float* __restrict__ gamma,
    const float* __restrict__ beta, unsigned short* __restrict__ out) {
  const int row = blockIdx.x;
  const int t = threadIdx.x;          // 256 threads x 8 elems = 2048
  const int lane = t & 63, wave = t >> 6;
  const unsigned short* rp = in + (long)row * 2048;
  short8 v8 = *(const short8*)&rp[t * 8];
  float v[8];
  float s = 0.f, s2 = 0.f;
#pragma unroll
  for (int j = 0; j < 8; ++j) {
    v[j] = bf2f((unsigned short)v8[j]);
    s += v[j];
    s2 += v[j] * v[j];
  }
#pragma unroll
  for (int off = 1; off < 64; off <<= 1) {
    s  += __shfl_xor(s, off);
    s2 += __shfl_xor(s2, off);
  }
  __shared__ float red[8];
  if (lane == 0) { red[wave] = s; red[4 + wave] = s2; }
  __syncthreads();
  float ts  = red[0] + red[1] + red[2] + red[3];
  float ts2 = red[4] + red[5] + red[6] + red[7];
  float mean = ts * (1.0f / 2048.0f);
  float var  = ts2 * (1.0f / 2048.0f) - mean * mean;
  float inv  = rsqrtf(var + 1e-5f);
  short8 o8;
#pragma unroll
  for (int j = 0; j < 8; ++j) {
    float o = (v[j] - mean) * inv * gamma[t * 8 + j] + beta[t * 8 + j];
    o8[j] = (short)f2bf(o);
  }
  *(short8*)(out + (long)row * 2048 + t * 8) = o8;
}

// --------------------------------------------------------------------------
extern "C" void kernel_launch(void* const* d_in, const int* in_sizes, int n_in,
                              void* d_out, int out_size, void* d_ws, size_t ws_size,
                              hipStream_t stream) {
  const float* graph    = (const float*)d_in[0];
  const float* temporal = (const float*)d_in[1];
  const float* gp_w  = (const float*)d_in[2];
  const float* gp_b  = (const float*)d_in[3];
  const float* tp_w  = (const float*)d_in[4];
  const float* tp_b  = (const float*)d_in[5];
  const float* in1_w = (const float*)d_in[6];
  const float* in1_b = (const float*)d_in[7];
  const float* out1_w = (const float*)d_in[8];
  const float* out1_b = (const float*)d_in[9];
  const float* in2_w = (const float*)d_in[10];
  const float* in2_b = (const float*)d_in[11];
  const float* out2_w = (const float*)d_in[12];
  const float* out2_b = (const float*)d_in[13];
  const float* gate_w = (const float*)d_in[14];
  const float* gate_b = (const float*)d_in[15];
  const float* ln_g  = (const float*)d_in[16];
  const float* ln_b  = (const float*)d_in[17];
  const float* lin_w = (const float*)d_in[18];
  const float* lin_b = (const float*)d_in[19];

  const int Bm = 16384, F = 2048, GD = 1024;
  const long BF = (long)Bm * F;      // 33,554,432

  // ws layout (~265 MB, same footprint as passing r0 kernel):
  unsigned short* S0  = (unsigned short*)d_ws;   // g -> ln_out
  unsigned short* S1  = S0 + BF;                 // t -> cross
  unsigned short* inG = S1 + BF;
  unsigned short* inT = inG + (long)Bm * GD;
  unsigned short* wGP   = inT + (long)Bm * GD;
  unsigned short* wTP   = wGP + (long)F * GD;
  unsigned short* wV1   = wTP + (long)F * GD;
  unsigned short* wO1   = wV1 + (long)F * F;
  unsigned short* wV2   = wO1 + (long)F * F;
  unsigned short* wO2   = wV2 + (long)F * F;
  unsigned short* wGATE = wO2 + (long)F * F;
  unsigned short* wLIN  = wGATE + (long)F * 2 * F;
  // d_out (134MB fp32) doubles as bf16 scratch until final GEMM:
  unsigned short* S2 = (unsigned short*)d_out;  // v1 -> preLN
  unsigned short* S3 = S2 + BF;                 // v2

  auto conv = [&](const float* src, unsigned short* dst, long n) {
    conv_kernel<<<dim3((unsigned)((n / 8 + 255) / 256)), 256, 0, stream>>>(src, dst, (int)n);
  };
  conv(graph, inG, (long)Bm * GD);
  conv(temporal, inT, (long)Bm * GD);
  conv(gp_w, wGP, (long)F * GD);
  conv(tp_w, wTP, (long)F * GD);
  conv(in1_w + (long)2 * F * F, wV1, (long)F * F);   // v-slice only (softmax==1)
  conv(out1_w, wO1, (long)F * F);
  conv(in2_w + (long)2 * F * F, wV2, (long)F * F);
  conv(out2_w, wO2, (long)F * F);
  conv(gate_w, wGATE, (long)F * 2 * F);
  conv(lin_w, wLIN, (long)F * F);

  dim3 blk(512);
  dim3 grid(512);   // 8 n-tiles x 64 m-tiles

  // K1: g = graph @ gp_w^T + gp_b        (K=1024) -> S0
  gemm256_kernel<EPI_BIAS><<<grid, blk, 0, stream>>>(inG, inG, GD, wGP, wGP, GD,
      GD, GD, gp_b, nullptr, nullptr, nullptr, S0);
  // K2: t = temporal @ tp_w^T + tp_b     (K=1024) -> S1
  gemm256_kernel<EPI_BIAS><<<grid, blk, 0, stream>>>(inT, inT, GD, wTP, wTP, GD,
      GD, GD, tp_b, nullptr, nullptr, nullptr, S1);
  // K3: v1 = t @ wv1^T + bv1             (K=2048) -> S2
  gemm256_kernel<EPI_BIAS><<<grid, blk, 0, stream>>>(S1, S1, F, wV1, wV1, F,
      F, F, in1_b + 2 * F, nullptr, nullptr, nullptr, S2);
  // K4: v2 = g @ wv2^T + bv2             (K=2048) -> S3
  gemm256_kernel<EPI_BIAS><<<grid, blk, 0, stream>>>(S0, S0, F, wV2, wV2, F,
      F, F, in2_b + 2 * F, nullptr, nullptr, nullptr, S3);
  // K5: cross = [v1|v2] @ [wO1;wO2]^T + out1_b + out2_b   (K=4096) -> S1
  gemm256_kernel<EPI_BIAS><<<grid, blk, 0, stream>>>(S2, S3, F, wO1, wO2, F,
      2 * F, F, out1_b, out2_b, nullptr, nullptr, S1);
  // K6: preLN = gatefuse([g|cross] @ gate_w^T + gate_b)   (K=4096) -> S2
  gemm256_kernel<EPI_GATE><<<grid, blk, 0, stream>>>(S0, S1, F, wGATE, wGATE + F, 2 * F,
      2 * F, F, gate_b, nullptr, S0, S1, S2);
  // K7: LayerNorm S2 -> S0
  ln_kernel<<<dim3(Bm), dim3(256), 0, stream>>>(S2, ln_g, ln_b, S0);
  // K8: out = ln @ lin_w^T + lin_b       (K=2048, fp32 out) -> d_out
  gemm256_kernel<EPI_F32><<<grid, blk, 0, stream>>>(S0, S0, F, wLIN, wLIN, F,
      F, F, lin_b, nullptr, nullptr, nullptr, (void*)d_out);
}

// Round 3
// 1150.914 us; speedup vs baseline: 1.3366x; 1.1763x over previous
//
#include <hip/hip_runtime.h>
#include <stdint.h>

typedef __attribute__((ext_vector_type(8))) short short8;
typedef __attribute__((ext_vector_type(4))) float f32x4;

__device__ __forceinline__ unsigned short f2bf(float f) {
  union { float f; uint32_t u; } v; v.f = f;
  uint32_t u = v.u;
  u += 0x7FFF + ((u >> 16) & 1);   // round-to-nearest-even
  return (unsigned short)(u >> 16);
}
__device__ __forceinline__ float bf2f(unsigned short h) {
  union { uint32_t u; float f; } v; v.u = ((uint32_t)h) << 16;
  return v.f;
}

// ---------------- convert fp32 -> bf16 (vectorized, 8 elems/thread) -------
__global__ void conv_kernel(const float* __restrict__ in,
                            unsigned short* __restrict__ out, int n) {
  long i = ((long)blockIdx.x * blockDim.x + threadIdx.x) * 8;
  if (i >= n) return;
  float4 a = *(const float4*)(in + i);
  float4 b = *(const float4*)(in + i + 4);
  short8 s;
  s[0] = (short)f2bf(a.x); s[1] = (short)f2bf(a.y);
  s[2] = (short)f2bf(a.z); s[3] = (short)f2bf(a.w);
  s[4] = (short)f2bf(b.x); s[5] = (short)f2bf(b.y);
  s[6] = (short)f2bf(b.z); s[7] = (short)f2bf(b.w);
  *(short8*)(out + i) = s;
}

// ---------------- 256x256 bf16 GEMM, 8-phase schedule ---------------------
// C = A @ W^T (+ epilogue). BK=64, 8 waves (2M x 4N), wave out 128x64 with
// INTERLEAVED frag mapping: A frag m -> row (m>>2)*128+(m&3)*32+wm*16,
// B frag n -> col (n>>1)*128+(n&1)*64+wn*16. So quadrant (mq,nq) of the
// K-tile touches exactly LDS halves (A[mq], B[nq]) for ALL waves ->
// half-tiles free up phase-by-phase and can be restaged with counted vmcnt.
// LDS: 2 buffers x (A:2 halves + B:2 halves) x 16KB = 128KB, chunk-XOR
// swizzled (p = c ^ (row&7)) with inverse-swizzled global source.
enum { EPI_BIAS = 0, EPI_GATE = 2, EPI_F32 = 3 };

#define VMW(N) asm volatile("s_waitcnt vmcnt(" #N ")" ::: "memory")
#define SBAR_FULL()                        \
  __builtin_amdgcn_sched_barrier(0);       \
  __builtin_amdgcn_s_barrier();            \
  __builtin_amdgcn_sched_barrier(0)

template <int EPI>
__global__ __launch_bounds__(512, 2)
void gemm8p_kernel(const unsigned short* __restrict__ A1,
                   const unsigned short* __restrict__ A2, int lda,
                   const unsigned short* __restrict__ W1,
                   const unsigned short* __restrict__ W2, int ldw,
                   int K, int KSPLIT,
                   const float* __restrict__ bias,
                   const float* __restrict__ bias2,
                   const unsigned short* __restrict__ Xg,
                   const unsigned short* __restrict__ Xc,
                   void* __restrict__ Cv) {
  constexpr int N = 2048;
  __shared__ unsigned short smem[65536];  // 128 KB

  const int tid = threadIdx.x, lane = tid & 63, w = tid >> 6;
  const int wm = w >> 2, wn = w & 3;

  // XCD-sliced swizzle: XCD x owns mt in [x*8, x*8+8), sweeps all 8 nt.
  const int xcd = blockIdx.x & 7, seq = blockIdx.x >> 3;
  const int nt = seq >> 3;
  const int mt = xcd * 8 + (seq & 7);
  const long tileM = (long)mt * 256, tileN = (long)nt * 256;

  // staging source geometry (per lane): region = w*2+j covers rows
  // w*16+j*8 .. +7 of a [128][64] half; lane l -> row +(l>>3),
  // logical chunk c = (l&7) ^ ((l>>3)&7)  (inverse of LDS chunk swizzle).
  const int sRow = w * 16 + (lane >> 3);
  const int sCol = (((lane & 7) ^ ((lane >> 3) & 7)) * 8);
  const unsigned short* aS1 = A1 + (tileM + sRow) * (long)lda + sCol;
  const unsigned short* aS2 = A2 + (tileM + sRow) * (long)lda + sCol;
  const unsigned short* bS1 = W1 + (tileN + sRow) * (long)ldw + sCol;
  const unsigned short* bS2 = W2 + (tileN + sRow) * (long)ldw + sCol;

  auto stage = [&](int op, int half, int d, int kt) {
    long k = (long)kt * 64;
    long ld = op ? (long)ldw : (long)lda;
    const unsigned short* p;
    if (op == 0) p = (k < KSPLIT) ? (aS1 + k) : (aS2 + (k - KSPLIT));
    else         p = (k < KSPLIT) ? (bS1 + k) : (bS2 + (k - KSPLIT));
    p += (long)half * 128 * ld;
    char* lp = (char*)smem + (d * 65536 + op * 32768 + half * 16384 + w * 2048);
    __builtin_amdgcn_global_load_lds(
        (const __attribute__((address_space(1))) void*)p,
        (__attribute__((address_space(3))) void*)lp, 16, 0, 0);
    __builtin_amdgcn_global_load_lds(
        (const __attribute__((address_space(1))) void*)(p + 8 * ld),
        (__attribute__((address_space(3))) void*)(lp + 1024), 16, 0, 0);
  };

  const int fr = lane & 15, kc = lane >> 4, l7 = lane & 7;
  auto rdA = [&](int d, int m, int kk) -> short8 {
    unsigned off = d * 65536 + (m >> 2) * 16384
                 + (((m & 3) * 32 + wm * 16 + fr) * 128)
                 + ((((kk * 4 + kc) ^ l7)) * 16);
    return *(const short8*)((const char*)smem + off);
  };
  auto rdB = [&](int d, int n, int kk) -> short8 {
    unsigned off = d * 65536 + 32768 + (n >> 1) * 16384
                 + (((n & 1) * 64 + wn * 16 + fr) * 128)
                 + ((((kk * 4 + kc) ^ l7)) * 16);
    return *(const short8*)((const char*)smem + off);
  };

  f32x4 acc[8][4] = {};
  short8 aH[4][2];

#define PHASE(D, MQ, NQ, LOADA, DOSTAGE, SOP, SHALF, SD, SKT)                 \
  {                                                                           \
    if (LOADA) {                                                              \
      _Pragma("unroll") for (int mi = 0; mi < 4; ++mi)                        \
      _Pragma("unroll") for (int kk = 0; kk < 2; ++kk)                        \
          aH[mi][kk] = rdA(D, (MQ)*4 + mi, kk);                               \
    }                                                                         \
    short8 bq[2][2];                                                          \
    _Pragma("unroll") for (int ni = 0; ni < 2; ++ni)                          \
    _Pragma("unroll") for (int kk = 0; kk < 2; ++kk)                          \
        bq[ni][kk] = rdB(D, (NQ)*2 + ni, kk);                                 \
    if (DOSTAGE) stage(SOP, SHALF, SD, SKT);                                  \
    SBAR_FULL();                                                              \
    __builtin_amdgcn_s_setprio(1);                                            \
    _Pragma("unroll") for (int mi = 0; mi < 4; ++mi)                          \
    _Pragma("unroll") for (int ni = 0; ni < 2; ++ni) {                        \
      acc[(MQ)*4+mi][(NQ)*2+ni] = __builtin_amdgcn_mfma_f32_16x16x32_bf16(    \
          aH[mi][0], bq[ni][0], acc[(MQ)*4+mi][(NQ)*2+ni], 0, 0, 0);          \
      acc[(MQ)*4+mi][(NQ)*2+ni] = __builtin_amdgcn_mfma_f32_16x16x32_bf16(    \
          aH[mi][1], bq[ni][1], acc[(MQ)*4+mi][(NQ)*2+ni], 0, 0, 0);          \
    }                                                                         \
    __builtin_amdgcn_s_setprio(0);                                            \
    __builtin_amdgcn_sched_barrier(0);                                        \
  }

  // ---- prologue: emulate steady-state aging order -------------------------
  stage(0, 0, 0, 0);  // b0.A0  tile0
  stage(1, 0, 0, 0);  // b0.B0  tile0
  stage(1, 1, 0, 0);  // b0.B1  tile0
  stage(0, 1, 0, 0);  // b0.A1  tile0
  stage(0, 0, 1, 1);  // b1.A0  tile1
  stage(1, 0, 1, 1);  // b1.B0  tile1
  VMW(8);             // forces b0.A0, b0.B0
  SBAR_FULL();

  const int NIT = K / 128;  // 2 K-tiles (BK=64) per iteration
  for (int it = 0; it < NIT - 1; ++it) {
    PHASE(0, 0, 0, 1, true, 1, 1, 1, 2 * it + 1); VMW(8); SBAR_FULL();
    PHASE(0, 0, 1, 0, true, 0, 0, 0, 2 * it + 2); VMW(8); SBAR_FULL();
    PHASE(0, 1, 0, 1, true, 0, 1, 1, 2 * it + 1);         SBAR_FULL();
    PHASE(0, 1, 1, 0, true, 1, 0, 0, 2 * it + 2); VMW(8); SBAR_FULL();
    PHASE(1, 0, 0, 1, true, 1, 1, 0, 2 * it + 2); VMW(8); SBAR_FULL();
    PHASE(1, 0, 1, 0, true, 0, 1, 0, 2 * it + 2); VMW(6); SBAR_FULL();
    PHASE(1, 1, 0, 1, true, 0, 0, 1, 2 * it + 3);         SBAR_FULL();
    PHASE(1, 1, 1, 0, true, 1, 0, 1, 2 * it + 3); VMW(8); SBAR_FULL();
  }
  {  // peeled last iteration (drain)
    const int itL = NIT - 1;
    PHASE(0, 0, 0, 1, true,  1, 1, 1, 2 * itL + 1); VMW(8); SBAR_FULL();
    PHASE(0, 0, 1, 0, false, 0, 0, 0, 0);           VMW(6); SBAR_FULL();
    PHASE(0, 1, 0, 1, true,  0, 1, 1, 2 * itL + 1);         SBAR_FULL();
    PHASE(0, 1, 1, 0, false, 0, 0, 0, 0);           VMW(4); SBAR_FULL();
    PHASE(1, 0, 0, 1, false, 0, 0, 0, 0);           VMW(2); SBAR_FULL();
    PHASE(1, 0, 1, 0, false, 0, 0, 0, 0);           VMW(0); SBAR_FULL();
    PHASE(1, 1, 0, 1, false, 0, 0, 0, 0);                   SBAR_FULL();
    PHASE(1, 1, 1, 0, false, 0, 0, 0, 0);
  }
#undef PHASE

  // ---- epilogue: C/D layout col = lane&15, row = (lane>>4)*4 + reg --------
  const int cr = (lane >> 4) * 4;
  const int cc = lane & 15;
#pragma unroll
  for (int m = 0; m < 8; ++m) {
    long rr = tileM + (m >> 2) * 128 + (m & 3) * 32 + wm * 16 + cr;
#pragma unroll
    for (int n = 0; n < 4; ++n) {
      long c = tileN + (n >> 1) * 128 + (n & 1) * 64 + wn * 16 + cc;
      float bv = (bias ? bias[c] : 0.0f) + (bias2 ? bias2[c] : 0.0f);
#pragma unroll
      for (int r = 0; r < 4; ++r) {
        long idx = (rr + r) * (long)N + c;
        float v = acc[m][n][r] + bv;
        if constexpr (EPI == EPI_GATE) {
          float gt = 1.0f / (1.0f + expf(-v));
          float gv = bf2f(Xg[idx]);   // g
          float cv = bf2f(Xc[idx]);   // cross
          v = gt * gv + (1.0f - gt) * cv + gv;  // fused + residual g
        }
        if constexpr (EPI == EPI_F32)
          ((float*)Cv)[idx] = v;
        else
          ((unsigned short*)Cv)[idx] = f2bf(v);
      }
    }
  }
}

// ---------------- row LayerNorm over 2048 cols ----------------------------
__global__ __launch_bounds__(256) void ln_kernel(
    const unsigned short* __restrict__ in, const float* __restrict__ gamma,
    const float* __restrict__ beta, unsigned short* __restrict__ out) {
  const int row = blockIdx.x;
  const int t = threadIdx.x;
  const int lane = t & 63, wave = t >> 6;
  const unsigned short* rp = in + (long)row * 2048;
  short8 v8 = *(const short8*)&rp[t * 8];
  float v[8];
  float s = 0.f, s2 = 0.f;
#pragma unroll
  for (int j = 0; j < 8; ++j) {
    v[j] = bf2f((unsigned short)v8[j]);
    s += v[j];
    s2 += v[j] * v[j];
  }
#pragma unroll
  for (int off = 1; off < 64; off <<= 1) {
    s  += __shfl_xor(s, off);
    s2 += __shfl_xor(s2, off);
  }
  __shared__ float red[8];
  if (lane == 0) { red[wave] = s; red[4 + wave] = s2; }
  __syncthreads();
  float ts  = red[0] + red[1] + red[2] + red[3];
  float ts2 = red[4] + red[5] + red[6] + red[7];
  float mean = ts * (1.0f / 2048.0f);
  float var  = ts2 * (1.0f / 2048.0f) - mean * mean;
  float inv  = rsqrtf(var + 1e-5f);
  short8 o8;
#pragma unroll
  for (int j = 0; j < 8; ++j) {
    float o = (v[j] - mean) * inv * gamma[t * 8 + j] + beta[t * 8 + j];
    o8[j] = (short)f2bf(o);
  }
  *(short8*)(out + (long)row * 2048 + t * 8) = o8;
}

// --------------------------------------------------------------------------
extern "C" void kernel_launch(void* const* d_in, const int* in_sizes, int n_in,
                              void* d_out, int out_size, void* d_ws, size_t ws_size,
                              hipStream_t stream) {
  const float* graph    = (const float*)d_in[0];
  const float* temporal = (const float*)d_in[1];
  const float* gp_w  = (const float*)d_in[2];
  const float* gp_b  = (const float*)d_in[3];
  const float* tp_w  = (const float*)d_in[4];
  const float* tp_b  = (const float*)d_in[5];
  const float* in1_w = (const float*)d_in[6];
  const float* in1_b = (const float*)d_in[7];
  const float* out1_w = (const float*)d_in[8];
  const float* out1_b = (const float*)d_in[9];
  const float* in2_w = (const float*)d_in[10];
  const float* in2_b = (const float*)d_in[11];
  const float* out2_w = (const float*)d_in[12];
  const float* out2_b = (const float*)d_in[13];
  const float* gate_w = (const float*)d_in[14];
  const float* gate_b = (const float*)d_in[15];
  const float* ln_g  = (const float*)d_in[16];
  const float* ln_b  = (const float*)d_in[17];
  const float* lin_w = (const float*)d_in[18];
  const float* lin_b = (const float*)d_in[19];

  const int Bm = 16384, F = 2048, GD = 1024;
  const long BF = (long)Bm * F;

  unsigned short* S0  = (unsigned short*)d_ws;   // g -> ln_out
  unsigned short* S1  = S0 + BF;                 // t -> cross
  unsigned short* inG = S1 + BF;
  unsigned short* inT = inG + (long)Bm * GD;
  unsigned short* wGP   = inT + (long)Bm * GD;
  unsigned short* wTP   = wGP + (long)F * GD;
  unsigned short* wV1   = wTP + (long)F * GD;
  unsigned short* wO1   = wV1 + (long)F * F;
  unsigned short* wV2   = wO1 + (long)F * F;
  unsigned short* wO2   = wV2 + (long)F * F;
  unsigned short* wGATE = wO2 + (long)F * F;
  unsigned short* wLIN  = wGATE + (long)F * 2 * F;
  unsigned short* S2 = (unsigned short*)d_out;  // v1 -> preLN
  unsigned short* S3 = S2 + BF;                 // v2

  auto conv = [&](const float* src, unsigned short* dst, long n) {
    conv_kernel<<<dim3((unsigned)((n / 8 + 255) / 256)), 256, 0, stream>>>(src, dst, (int)n);
  };
  conv(graph, inG, (long)Bm * GD);
  conv(temporal, inT, (long)Bm * GD);
  conv(gp_w, wGP, (long)F * GD);
  conv(tp_w, wTP, (long)F * GD);
  conv(in1_w + (long)2 * F * F, wV1, (long)F * F);   // v-slice only (softmax==1)
  conv(out1_w, wO1, (long)F * F);
  conv(in2_w + (long)2 * F * F, wV2, (long)F * F);
  conv(out2_w, wO2, (long)F * F);
  conv(gate_w, wGATE, (long)F * 2 * F);
  conv(lin_w, wLIN, (long)F * F);

  dim3 blk(512);
  dim3 grid(512);  // 8 XCD-slices x (8 nt x 8 mt)

  // K1: g = graph @ gp_w^T + gp_b        (K=1024) -> S0
  gemm8p_kernel<EPI_BIAS><<<grid, blk, 0, stream>>>(inG, inG, GD, wGP, wGP, GD,
      GD, GD, gp_b, nullptr, nullptr, nullptr, S0);
  // K2: t = temporal @ tp_w^T + tp_b     (K=1024) -> S1
  gemm8p_kernel<EPI_BIAS><<<grid, blk, 0, stream>>>(inT, inT, GD, wTP, wTP, GD,
      GD, GD, tp_b, nullptr, nullptr, nullptr, S1);
  // K3: v1 = t @ wv1^T + bv1             (K=2048) -> S2
  gemm8p_kernel<EPI_BIAS><<<grid, blk, 0, stream>>>(S1, S1, F, wV1, wV1, F,
      F, F, in1_b + 2 * F, nullptr, nullptr, nullptr, S2);
  // K4: v2 = g @ wv2^T + bv2             (K=2048) -> S3
  gemm8p_kernel<EPI_BIAS><<<grid, blk, 0, stream>>>(S0, S0, F, wV2, wV2, F,
      F, F, in2_b + 2 * F, nullptr, nullptr, nullptr, S3);
  // K5: cross = [v1|v2] @ [wO1;wO2]^T + out1_b + out2_b   (K=4096) -> S1
  gemm8p_kernel<EPI_BIAS><<<grid, blk, 0, stream>>>(S2, S3, F, wO1, wO2, F,
      2 * F, F, out1_b, out2_b, nullptr, nullptr, S1);
  // K6: preLN = gatefuse([g|cross] @ gate_w^T + gate_b)   (K=4096) -> S2
  gemm8p_kernel<EPI_GATE><<<grid, blk, 0, stream>>>(S0, S1, F, wGATE, wGATE + F, 2 * F,
      2 * F, F, gate_b, nullptr, S0, S1, S2);
  // K7: LayerNorm S2 -> S0
  ln_kernel<<<dim3(Bm), dim3(256), 0, stream>>>(S2, ln_g, ln_b, S0);
  // K8: out = ln @ lin_w^T + lin_b       (K=2048, fp32 out) -> d_out
  gemm8p_kernel<EPI_F32><<<grid, blk, 0, stream>>>(S0, S0, F, wLIN, wLIN, F,
      F, F, lin_b, nullptr, nullptr, nullptr, (void*)d_out);
}